// Round 9
// baseline (314.480 us; speedup 1.0000x reference)
//
#include <hip/hip_runtime.h>
#include <math.h>

#define BB 8
#define CCH 256
#define QQ 4
#define NN 1600          // H*W
#define BQN 32           // B*Q
#define SP 51200         // BQN*NN
#define EPSF 1e-5f

typedef __attribute__((ext_vector_type(8))) short bf16x8;  // 8 bf16 (4 VGPRs)
typedef __attribute__((ext_vector_type(4))) float f32x4;

static __device__ inline ushort f2bf(float f) {
  union { float f; unsigned u; } v; v.f = f;
  return (ushort)((v.u + 0x7fffu + ((v.u >> 16) & 1u)) >> 16);  // RNE
}
static __device__ inline float bf2f(ushort u) {
  union { unsigned u; float f; } v; v.u = ((unsigned)u) << 16;
  return v.f;
}
// async 16B global->LDS (lane-linear dest)
static __device__ inline void gld16(const ushort* g, ushort* l) {
  __builtin_amdgcn_global_load_lds(
      (const __attribute__((address_space(1))) unsigned int*)g,
      (__attribute__((address_space(3))) unsigned int*)l, 16, 0, 0);
}

// ---------------- fake-quant weights -> bf16 (wv transposed), gamma, zero accumulators ----------------
__global__ void quant_weights_kernel(const float* Wq, const float* Wk,
                                     const float* Wv, const float* Wp,
                                     const float* gamma,
                                     ushort* wq, ushort* wk, ushort* wvT, ushort* wp,
                                     float* gq, float* r, float* diagacc, float* tracc) {
  __shared__ float red[256];
  int blk = blockIdx.x;
  int tid = threadIdx.x;
  if (blk < 1024) {
    int mat = blk >> 8;
    int row = blk & 255;
    const float* W = (mat == 0) ? Wq : (mat == 1) ? Wk : (mat == 2) ? Wv : Wp;
    float w = W[row * 256 + tid];
    red[tid] = fabsf(w);
    __syncthreads();
    for (int s = 128; s > 0; s >>= 1) {
      if (tid < s) red[tid] = fmaxf(red[tid], red[tid + s]);
      __syncthreads();
    }
    float s = red[0] / 127.0f + 1e-8f;
    float q = fminf(fmaxf(rintf(w / s), -127.0f), 127.0f) * s;
    ushort qb = f2bf(q);
    if (mat == 0)      wq[row * 256 + tid] = qb;
    else if (mat == 1) wk[row * 256 + tid] = qb;
    else if (mat == 2) wvT[tid * 256 + row] = qb;   // transposed: wvT[i][d]=Wv[d][i]
    else               wp[row * 256 + tid] = qb;
  } else {
    float g = gamma[tid];
    red[tid] = fabsf(g);
    __syncthreads();
    for (int s = 128; s > 0; s >>= 1) {
      if (tid < s) red[tid] = fmaxf(red[tid], red[tid + s]);
      __syncthreads();
    }
    float s = red[0] / 127.0f + 1e-8f;
    gq[tid] = fminf(fmaxf(rintf(g / s), -127.0f), 127.0f) * s;
    for (int i = tid; i < BQN * 256; i += 256) {
      r[i] = 0.f; diagacc[i] = 0.f; tracc[i] = 0.f;
    }
  }
}

// ---------------- prep: x fp32 -> xb[bq][c][n] bf16 + xT[s][c] bf16 + r row-sums (bf16-consistent) ----------------
__global__ __launch_bounds__(256)
void prep_kernel(const float* __restrict__ x, ushort* __restrict__ xb,
                 ushort* __restrict__ xT, float* __restrict__ r) {
  int bqi = blockIdx.z, b = bqi >> 2, q = bqi & 3;
  int s0 = blockIdx.x * 64, c0 = blockIdx.y * 64;
  __shared__ ushort lT[64 * 66];
  int tid = threadIdx.x;
  int c = tid >> 2, nch = (tid & 3) * 16;
  const float* xp = x + ((size_t)(b * CCH + c0 + c) * QQ + q) * NN + s0 + nch;
  union { ushort u[16]; int4 v[2]; } nb;
  float s = 0.f;
#pragma unroll
  for (int j = 0; j < 4; j++) {
    float4 f = ((const float4*)xp)[j];
    nb.u[j * 4 + 0] = f2bf(f.x);
    nb.u[j * 4 + 1] = f2bf(f.y);
    nb.u[j * 4 + 2] = f2bf(f.z);
    nb.u[j * 4 + 3] = f2bf(f.w);
#pragma unroll
    for (int t = 0; t < 4; t++) {
      s += bf2f(nb.u[j * 4 + t]);
      lT[c * 66 + nch + j * 4 + t] = nb.u[j * 4 + t];
    }
  }
  ushort* xbp = xb + (size_t)bqi * (CCH * NN) + (size_t)(c0 + c) * NN + s0 + nch;
  *(int4*)xbp = nb.v[0];
  *((int4*)xbp + 1) = nb.v[1];
  s += __shfl_down(s, 2);
  s += __shfl_down(s, 1);
  if ((tid & 3) == 0) atomicAdd(&r[bqi * 256 + c0 + c], s);
  __syncthreads();
  int n = tid >> 2, cch = (tid & 3) * 16;
  union { ushort u[16]; int4 v[2]; } o;
#pragma unroll
  for (int i = 0; i < 16; i++) o.u[i] = lT[(cch + i) * 66 + n];
  ushort* dst = xT + (size_t)(bqi * NN + s0 + n) * CCH + c0 + cch;
  *(int4*)dst = o.v[0];
  *((int4*)dst + 1) = o.v[1];
}

// ---------------- gram split-K partials: Gp[z=chunk*32+bq] += Xb Xb^T over k-chunk ----------------
__global__ __launch_bounds__(256)
void gram_part_kernel(const ushort* __restrict__ xb, float* __restrict__ Gp) {
  __shared__ __align__(16) char smem[32768];
  int z = blockIdx.z;
  int bq = z & 31, chunk = z >> 5;
  int kbase = chunk * 416;
  int Kc = 1600 - kbase; if (Kc > 416) Kc = 416;
  int mBase = blockIdx.y * 128, nBase = blockIdx.x * 128;
  int tid = threadIdx.x, wave = tid >> 6, lane = tid & 63;
  int wm = wave >> 1, wn = wave & 1;
  int col = lane & 15, quad = lane >> 4;
  int srow = tid >> 2, skc = (tid & 3) * 8;
  const ushort* X = xb + (size_t)bq * (CCH * NN) + kbase;
  const ushort* gA  = X + (size_t)(mBase + srow) * NN + skc;
  const ushort* gA2 = gA + (size_t)64 * NN;
  const ushort* gB  = X + (size_t)(nBase + srow) * NN + skc;
  const ushort* gB2 = gB + (size_t)64 * NN;
  ushort* sA1[2]; ushort* sA2[2]; ushort* sB1[2]; ushort* sB2[2];
#pragma unroll
  for (int b = 0; b < 2; b++) {
    ushort* lAb = (ushort*)(smem + b * 16384);
    ushort* lBb = (ushort*)(smem + b * 16384 + 8192);
    sA1[b] = &lAb[srow * 32 + skc];
    sA2[b] = &lAb[(64 + srow) * 32 + skc];
    sB1[b] = &lBb[srow * 32 + skc];
    sB2[b] = &lBb[(64 + srow) * 32 + skc];
  }
  f32x4 acc[4][4];
#pragma unroll
  for (int i = 0; i < 4; i++)
#pragma unroll
    for (int j = 0; j < 4; j++) acc[i][j] = (f32x4){0.f, 0.f, 0.f, 0.f};

  int nIter = Kc >> 5;
  gld16(gA, sA1[0]); gld16(gA2, sA2[0]); gld16(gB, sB1[0]); gld16(gB2, sB2[0]);
  for (int it = 0; it < nIter; ++it) {
    int cur = it & 1;
    __syncthreads();
    if (it + 1 < nIter) {
      int kt = (it + 1) << 5, nxt = cur ^ 1;
      gld16(gA + kt, sA1[nxt]); gld16(gA2 + kt, sA2[nxt]);
      gld16(gB + kt, sB1[nxt]); gld16(gB2 + kt, sB2[nxt]);
    }
    const ushort* lAc = (const ushort*)(smem + cur * 16384);
    const ushort* lBc = (const ushort*)(smem + cur * 16384 + 8192);
    bf16x8 af[4], bfr[4];
#pragma unroll
    for (int i = 0; i < 4; i++)
      af[i] = *(const bf16x8*)&lAc[(wm * 64 + i * 16 + col) * 32 + quad * 8];
#pragma unroll
    for (int j = 0; j < 4; j++)
      bfr[j] = *(const bf16x8*)&lBc[(wn * 64 + j * 16 + col) * 32 + quad * 8];
#pragma unroll
    for (int i = 0; i < 4; i++)
#pragma unroll
      for (int j = 0; j < 4; j++)
        acc[i][j] = __builtin_amdgcn_mfma_f32_16x16x32_bf16(af[i], bfr[j], acc[i][j], 0, 0, 0);
  }
  // direct fp32 store in C-layout coords (no staging needed; 64B segments/quad)
  float* G = Gp + (size_t)z * 65536;
#pragma unroll
  for (int i = 0; i < 4; i++)
#pragma unroll
    for (int j = 0; j < 4; j++)
#pragma unroll
      for (int rg = 0; rg < 4; rg++) {
        int row = mBase + wm * 64 + i * 16 + quad * 4 + rg;
        int cl  = nBase + wn * 64 + j * 16 + col;
        G[row * 256 + cl] = acc[i][j][rg];
      }
}

// ---------------- gram reduce: sum 4 chunks -> split bf16 Gh+Gl ----------------
__global__ __launch_bounds__(256)
void gram_reduce_kernel(const float* __restrict__ Gp, ushort* __restrict__ Gh,
                        ushort* __restrict__ Gl) {
  int bq = blockIdx.x, tid = threadIdx.x;
  const size_t cs = (size_t)32 * 65536;
  for (int k = 0; k < 32; k++) {
    size_t f8 = (size_t)(tid + k * 256) * 8;   // 8-elem chunk
    size_t base = (size_t)bq * 65536 + f8;
    union { ushort u[8]; int4 v; } oh, ol;
#pragma unroll
    for (int t = 0; t < 8; t += 4) {
      float4 a = *(const float4*)(Gp + base + t);
      float4 b = *(const float4*)(Gp + cs + base + t);
      float4 c = *(const float4*)(Gp + 2 * cs + base + t);
      float4 d = *(const float4*)(Gp + 3 * cs + base + t);
      float v0 = a.x + b.x + c.x + d.x;
      float v1 = a.y + b.y + c.y + d.y;
      float v2 = a.z + b.z + c.z + d.z;
      float v3 = a.w + b.w + c.w + d.w;
      ushort h0 = f2bf(v0), h1 = f2bf(v1), h2 = f2bf(v2), h3 = f2bf(v3);
      oh.u[t] = h0; oh.u[t + 1] = h1; oh.u[t + 2] = h2; oh.u[t + 3] = h3;
      ol.u[t] = f2bf(v0 - bf2f(h0)); ol.u[t + 1] = f2bf(v1 - bf2f(h1));
      ol.u[t + 2] = f2bf(v2 - bf2f(h2)); ol.u[t + 3] = f2bf(v3 - bf2f(h3));
    }
    *(int4*)(Gh + base) = oh.v;
    *(int4*)(Gl + base) = ol.v;
  }
}

// ---------------- small 256x256x256 GEMMs: C = A * B^T (per z) ----------------
// MODE 0: M1 = wq * (Gh+Gl)^T  -> dual bf16 (M1h, M1l)
// MODE 1: S  = (M1h+M1l) * wk^T -> fp32
// MODE 2: N1 = P * wvT^T        -> bf16 transposed [n][m]
// MODE 3: T  = wp * N1^T        -> bf16 [m][n]
template<int MODE>
__global__ __launch_bounds__(256)
void gemm256(const ushort* __restrict__ A, long sA, const ushort* __restrict__ A2,
             const ushort* __restrict__ B, long sB, const ushort* __restrict__ B2,
             void* __restrict__ C1, void* __restrict__ C2, long sC) {
  __shared__ __align__(16) char smem[24576];
  ushort* lA = (ushort*)smem;
  ushort* lB = (ushort*)(smem + 8192);
  ushort* lX = (ushort*)(smem + 16384);
  float* lC = (float*)smem;
  int z = blockIdx.z;
  int mBase = blockIdx.y * 128, nBase = blockIdx.x * 128;
  int tid = threadIdx.x, wave = tid >> 6, lane = tid & 63;
  int wm = wave >> 1, wn = wave & 1;
  int col = lane & 15, quad = lane >> 4;
  int srow = tid >> 2, skc = (tid & 3) * 8;
  const ushort* Az = A + (size_t)z * sA;
  const ushort* Bz = B + (size_t)z * sB;
  const ushort* gA  = Az + (size_t)(mBase + srow) * 256 + skc;
  const ushort* gA2r = gA + 64 * 256;
  const ushort* gB  = Bz + (size_t)(nBase + srow) * 256 + skc;
  const ushort* gB2r = gB + 64 * 256;
  const ushort* gX = nullptr;
  const ushort* gX2 = nullptr;
  if (MODE == 0) {
    const ushort* Xz = B2 + (size_t)z * sB;
    gX = Xz + (size_t)(nBase + srow) * 256 + skc;
    gX2 = gX + 64 * 256;
  } else if (MODE == 1) {
    const ushort* Xz = A2 + (size_t)z * sA;
    gX = Xz + (size_t)(mBase + srow) * 256 + skc;
    gX2 = gX + 64 * 256;
  }
  ushort* dA1 = &lA[srow * 32 + skc]; ushort* dA2 = &lA[(64 + srow) * 32 + skc];
  ushort* dB1 = &lB[srow * 32 + skc]; ushort* dB2 = &lB[(64 + srow) * 32 + skc];
  ushort* dX1 = &lX[srow * 32 + skc]; ushort* dX2 = &lX[(64 + srow) * 32 + skc];

  f32x4 acc[4][4];
#pragma unroll
  for (int i = 0; i < 4; i++)
#pragma unroll
    for (int j = 0; j < 4; j++) acc[i][j] = (f32x4){0.f, 0.f, 0.f, 0.f};

  for (int kt = 0; kt < 256; kt += 32) {
    __syncthreads();
    gld16(gA + kt, dA1); gld16(gA2r + kt, dA2);
    gld16(gB + kt, dB1); gld16(gB2r + kt, dB2);
    if (MODE <= 1) { gld16(gX + kt, dX1); gld16(gX2 + kt, dX2); }
    __syncthreads();
    bf16x8 af[4], bfr[4], xf[4];
#pragma unroll
    for (int i = 0; i < 4; i++)
      af[i] = *(const bf16x8*)&lA[(wm * 64 + i * 16 + col) * 32 + quad * 8];
#pragma unroll
    for (int j = 0; j < 4; j++)
      bfr[j] = *(const bf16x8*)&lB[(wn * 64 + j * 16 + col) * 32 + quad * 8];
    if (MODE == 0) {
#pragma unroll
      for (int j = 0; j < 4; j++)
        xf[j] = *(const bf16x8*)&lX[(wn * 64 + j * 16 + col) * 32 + quad * 8];
    } else if (MODE == 1) {
#pragma unroll
      for (int i = 0; i < 4; i++)
        xf[i] = *(const bf16x8*)&lX[(wm * 64 + i * 16 + col) * 32 + quad * 8];
    }
#pragma unroll
    for (int i = 0; i < 4; i++)
#pragma unroll
      for (int j = 0; j < 4; j++) {
        acc[i][j] = __builtin_amdgcn_mfma_f32_16x16x32_bf16(af[i], bfr[j], acc[i][j], 0, 0, 0);
        if (MODE == 0)
          acc[i][j] = __builtin_amdgcn_mfma_f32_16x16x32_bf16(af[i], xf[j], acc[i][j], 0, 0, 0);
        else if (MODE == 1)
          acc[i][j] = __builtin_amdgcn_mfma_f32_16x16x32_bf16(xf[i], bfr[j], acc[i][j], 0, 0, 0);
      }
  }
  __syncthreads();
  float* lCw = lC + wave * 16 * 68;
  int mW = mBase + wm * 64, nW = nBase + wn * 64;
#pragma unroll
  for (int i = 0; i < 4; i++) {
#pragma unroll
    for (int j = 0; j < 4; j++)
#pragma unroll
      for (int rg = 0; rg < 4; rg++)
        lCw[(quad * 4 + rg) * 68 + j * 16 + col] = acc[i][j][rg];
    int mrow0 = mW + i * 16;
    int rr = lane & 15, cc = lane >> 4;
    if (MODE == 0) {
      union { ushort u[16]; int4 v[2]; } oh, ol;
#pragma unroll
      for (int t = 0; t < 16; t++) {
        float vfl = lCw[rr * 68 + cc * 16 + t];
        ushort hh = f2bf(vfl);
        oh.u[t] = hh;
        ol.u[t] = f2bf(vfl - bf2f(hh));
      }
      size_t off = (size_t)z * sC + (size_t)(mrow0 + rr) * 256 + nW + cc * 16;
      *(int4*)((ushort*)C1 + off) = oh.v[0];
      *((int4*)((ushort*)C1 + off) + 1) = oh.v[1];
      *(int4*)((ushort*)C2 + off) = ol.v[0];
      *((int4*)((ushort*)C2 + off) + 1) = ol.v[1];
    } else if (MODE == 1) {
      float* C = (float*)C1 + (size_t)z * sC + (size_t)(mrow0 + rr) * 256 + nW + cc * 16;
#pragma unroll
      for (int v = 0; v < 4; v++) {
        float4 f;
        f.x = lCw[rr * 68 + cc * 16 + v * 4 + 0];
        f.y = lCw[rr * 68 + cc * 16 + v * 4 + 1];
        f.z = lCw[rr * 68 + cc * 16 + v * 4 + 2];
        f.w = lCw[rr * 68 + cc * 16 + v * 4 + 3];
        *(float4*)(C + v * 4) = f;
      }
    } else if (MODE == 2) {
      int n = nW + lane;
      union { ushort u[16]; int4 v[2]; } o;
#pragma unroll
      for (int t = 0; t < 16; t++) o.u[t] = f2bf(lCw[t * 68 + lane]);
      ushort* C = (ushort*)C1 + (size_t)z * sC + (size_t)n * 256 + mrow0;
      *(int4*)C = o.v[0];
      *((int4*)C + 1) = o.v[1];
    } else {
      union { ushort u[16]; int4 v[2]; } o;
#pragma unroll
      for (int t = 0; t < 16; t++) o.u[t] = f2bf(lCw[rr * 68 + cc * 16 + t]);
      ushort* C = (ushort*)C1 + (size_t)z * sC + (size_t)(mrow0 + rr) * 256 + nW + cc * 16;
      *(int4*)C = o.v[0];
      *((int4*)C + 1) = o.v[1];
    }
  }
}

// ---------------- u = Wq*r, v = Wk*r (bias rank-1 helpers) ----------------
__global__ void uv_kernel(const ushort* __restrict__ wq, const ushort* __restrict__ wk,
                          const float* __restrict__ r, float* __restrict__ u,
                          float* __restrict__ vv) {
  int bq = blockIdx.x, sel = blockIdx.y, c = threadIdx.x;
  const ushort* W = sel ? wk : wq;
  float s = 0.f;
  for (int i = 0; i < 256; i++) s += bf2f(W[c * 256 + i]) * r[bq * 256 + i];
  (sel ? vv : u)[bq * 256 + c] = s;
}

// ---------------- softmax with bias rank-1 terms; emits P bf16 + pb = P.bv ----------------
__global__ void softmax_kernel(const float* __restrict__ S, const float* __restrict__ u,
                               const float* __restrict__ vv, const float* __restrict__ bqv,
                               const float* __restrict__ bkv, const float* __restrict__ bvv,
                               ushort* __restrict__ P, float* __restrict__ pb) {
  int bi = blockIdx.x;
  int bq = bi >> 8, rw = bi & 255;
  int tid = threadIdx.x;
  size_t off = (size_t)bq * 65536 + (size_t)rw * 256 + tid;
  float bqc = bqv[rw], bkd = bkv[tid];
  float val = 0.125f * (S[off] + u[bq * 256 + rw] * bkd + bqc * vv[bq * 256 + tid]
                        + 1600.0f * bqc * bkd);
  __shared__ float red[256];
  red[tid] = val;
  __syncthreads();
  for (int s = 128; s > 0; s >>= 1) {
    if (tid < s) red[tid] = fmaxf(red[tid], red[tid + s]);
    __syncthreads();
  }
  float m = red[0];
  __syncthreads();
  float e = expf(val - m);
  red[tid] = e;
  __syncthreads();
  for (int s = 128; s > 0; s >>= 1) {
    if (tid < s) red[tid] += red[tid + s];
    __syncthreads();
  }
  float p = e / red[0];
  P[off] = f2bf(p);
  __syncthreads();
  red[tid] = p * bvv[tid];
  __syncthreads();
  for (int s = 128; s > 0; s >>= 1) {
    if (tid < s) red[tid] += red[tid + s];
    __syncthreads();
  }
  if (tid == 0) pb[bq * 256 + rw] = red[0];
}

// ---------------- bo[bq][o] = Wp*pb + bp ----------------
__global__ void bo_kernel(const ushort* __restrict__ wp, const float* __restrict__ pb,
                          const float* __restrict__ bp, float* __restrict__ bo) {
  int bq = blockIdx.x, o = threadIdx.x;
  float s = bp[o];
  for (int c = 0; c < 256; c++) s += bf2f(wp[o * 256 + c]) * pb[bq * 256 + c];
  bo[bq * 256 + o] = s;
}

// ---------------- diag(T G T^T) + T.r via Y = T*(Gh+Gl), epilogue dots with T,r ----------------
__global__ __launch_bounds__(256)
void tgt_kernel(const ushort* __restrict__ Tm, const ushort* __restrict__ Gh,
                const ushort* __restrict__ Gl, const float* __restrict__ r,
                float* __restrict__ diagacc, float* __restrict__ tracc) {
  __shared__ __align__(16) char smem[24576];
  ushort* lA = (ushort*)smem;
  ushort* lB = (ushort*)(smem + 8192);
  ushort* lX = (ushort*)(smem + 16384);
  float* lC = (float*)smem;
  int z = blockIdx.z;
  int mBase = blockIdx.y * 128, nBase = blockIdx.x * 128;
  int tid = threadIdx.x, wave = tid >> 6, lane = tid & 63;
  int wm = wave >> 1, wn = wave & 1;
  int col = lane & 15, quad = lane >> 4;
  int srow = tid >> 2, skc = (tid & 3) * 8;
  const ushort* Az = Tm + (size_t)z * 65536;
  const ushort* Bz = Gh + (size_t)z * 65536;
  const ushort* Xz = Gl + (size_t)z * 65536;
  const ushort* gA  = Az + (size_t)(mBase + srow) * 256 + skc;
  const ushort* gA2r = gA + 64 * 256;
  const ushort* gB  = Bz + (size_t)(nBase + srow) * 256 + skc;
  const ushort* gB2r = gB + 64 * 256;
  const ushort* gX  = Xz + (size_t)(nBase + srow) * 256 + skc;
  const ushort* gX2 = gX + 64 * 256;
  ushort* dA1 = &lA[srow * 32 + skc]; ushort* dA2 = &lA[(64 + srow) * 32 + skc];
  ushort* dB1 = &lB[srow * 32 + skc]; ushort* dB2 = &lB[(64 + srow) * 32 + skc];
  ushort* dX1 = &lX[srow * 32 + skc]; ushort* dX2 = &lX[(64 + srow) * 32 + skc];

  f32x4 acc[4][4];
#pragma unroll
  for (int i = 0; i < 4; i++)
#pragma unroll
    for (int j = 0; j < 4; j++) acc[i][j] = (f32x4){0.f, 0.f, 0.f, 0.f};

  for (int kt = 0; kt < 256; kt += 32) {
    __syncthreads();
    gld16(gA + kt, dA1); gld16(gA2r + kt, dA2);
    gld16(gB + kt, dB1); gld16(gB2r + kt, dB2);
    gld16(gX + kt, dX1); gld16(gX2 + kt, dX2);
    __syncthreads();
    bf16x8 af[4], bfr[4], xf[4];
#pragma unroll
    for (int i = 0; i < 4; i++)
      af[i] = *(const bf16x8*)&lA[(wm * 64 + i * 16 + col) * 32 + quad * 8];
#pragma unroll
    for (int j = 0; j < 4; j++) {
      bfr[j] = *(const bf16x8*)&lB[(wn * 64 + j * 16 + col) * 32 + quad * 8];
      xf[j]  = *(const bf16x8*)&lX[(wn * 64 + j * 16 + col) * 32 + quad * 8];
    }
#pragma unroll
    for (int i = 0; i < 4; i++)
#pragma unroll
      for (int j = 0; j < 4; j++) {
        acc[i][j] = __builtin_amdgcn_mfma_f32_16x16x32_bf16(af[i], bfr[j], acc[i][j], 0, 0, 0);
        acc[i][j] = __builtin_amdgcn_mfma_f32_16x16x32_bf16(af[i], xf[j], acc[i][j], 0, 0, 0);
      }
  }
  __syncthreads();
  float* lCw = lC + wave * 16 * 68;
  int mW = mBase + wm * 64, nW = nBase + wn * 64;
#pragma unroll
  for (int i = 0; i < 4; i++) {
#pragma unroll
    for (int j = 0; j < 4; j++)
#pragma unroll
      for (int rg = 0; rg < 4; rg++)
        lCw[(quad * 4 + rg) * 68 + j * 16 + col] = acc[i][j][rg];
    int mrow0 = mW + i * 16;
    int rr = lane & 15, cc = lane >> 4;
    // Y row (mrow0+rr), cols nW+cc*16 .. +16: dot with T and r
    const ushort* Trow = Tm + (size_t)z * 65536 + (size_t)(mrow0 + rr) * 256 + nW + cc * 16;
    const float* rrow = r + (size_t)z * 256 + nW + cc * 16;
    float sd = 0.f, st = 0.f;
#pragma unroll
    for (int t = 0; t < 16; t++) {
      float tv = bf2f(Trow[t]);
      sd += lCw[rr * 68 + cc * 16 + t] * tv;
      st += tv * rrow[t];
    }
    sd += __shfl_xor(sd, 16); sd += __shfl_xor(sd, 32);
    st += __shfl_xor(st, 16); st += __shfl_xor(st, 32);
    if (lane < 16) {
      atomicAdd(&diagacc[z * 256 + mrow0 + rr], sd);
      atomicAdd(&tracc[z * 256 + mrow0 + rr], st);
    }
  }
}

// ---------------- channel stats: mean, g = rsqrt(var+eps)*gamma_q ----------------
__global__ void chanstats_kernel(const float* __restrict__ diagacc,
                                 const float* __restrict__ tracc,
                                 const float* __restrict__ bo,
                                 const float* __restrict__ gq,
                                 float* __restrict__ stm, float* __restrict__ stg) {
  int o = threadIdx.x;
  float sd = 0.f, str = 0.f, sb = 0.f, spt = 0.f, sb2 = 0.f;
  for (int bq = 0; bq < BQN; bq++) {
    float d = diagacc[bq * 256 + o];
    float t = tracc[bq * 256 + o];
    float b = bo[bq * 256 + o];
    sd += d; str += t; sb += b; spt += b * t; sb2 += b * b;
  }
  float inv = 1.0f / (float)(BQN * NN);
  float mean = (str + (float)NN * sb) * inv;
  float e2 = (sd + 2.0f * spt + (float)NN * sb2) * inv;
  float var = e2 - mean * mean;
  stm[o] = mean;
  stg[o] = rsqrtf(var + EPSF) * gq[o];
}

// ---------------- final: out = ((T*X + bo) - mean)*g + beta, written directly ----------------
__global__ __launch_bounds__(256)
void final_kernel(const ushort* __restrict__ Tm, const ushort* __restrict__ xT,
                  const float* __restrict__ bo, const float* __restrict__ stm,
                  const float* __restrict__ stg, const float* __restrict__ beta,
                  float* __restrict__ out) {
  __shared__ __align__(16) char smem[32768];
  float* lC = (float*)smem;
  int z = blockIdx.z;
  int mBase = blockIdx.y * 128, nBase = blockIdx.x * 128;
  int tid = threadIdx.x, wave = tid >> 6, lane = tid & 63;
  int wm = wave >> 1, wn = wave & 1;
  int col = lane & 15, quad = lane >> 4;
  int srow = tid >> 2, skc = (tid & 3) * 8;
  const ushort* Az = Tm + (size_t)z * 65536;
  const ushort* Bz = xT + (size_t)z * (NN * 256);
  const ushort* gA  = Az + (size_t)(mBase + srow) * 256 + skc;
  const ushort* gA2 = gA + 64 * 256;
  int br1 = nBase + srow;      br1 = br1 < NN ? br1 : NN - 1;
  int br2 = nBase + 64 + srow; br2 = br2 < NN ? br2 : NN - 1;
  const ushort* gB  = Bz + (size_t)br1 * 256 + skc;
  const ushort* gB2 = Bz + (size_t)br2 * 256 + skc;
  ushort* sA1[2]; ushort* sA2[2]; ushort* sB1[2]; ushort* sB2[2];
#pragma unroll
  for (int b = 0; b < 2; b++) {
    ushort* lAb = (ushort*)(smem + b * 16384);
    ushort* lBb = (ushort*)(smem + b * 16384 + 8192);
    sA1[b] = &lAb[srow * 32 + skc];
    sA2[b] = &lAb[(64 + srow) * 32 + skc];
    sB1[b] = &lBb[srow * 32 + skc];
    sB2[b] = &lBb[(64 + srow) * 32 + skc];
  }
  f32x4 acc[4][4];
#pragma unroll
  for (int i = 0; i < 4; i++)
#pragma unroll
    for (int j = 0; j < 4; j++) acc[i][j] = (f32x4){0.f, 0.f, 0.f, 0.f};

  const int nIter = 8;  // K=256
  gld16(gA, sA1[0]); gld16(gA2, sA2[0]); gld16(gB, sB1[0]); gld16(gB2, sB2[0]);
  for (int it = 0; it < nIter; ++it) {
    int cur = it & 1;
    __syncthreads();
    if (it + 1 < nIter) {
      int kt = (it + 1) << 5, nxt = cur ^ 1;
      gld16(gA + kt, sA1[nxt]); gld16(gA2 + kt, sA2[nxt]);
      gld16(gB + kt, sB1[nxt]); gld16(gB2 + kt, sB2[nxt]);
    }
    const ushort* lAc = (const ushort*)(smem + cur * 16384);
    const ushort* lBc = (const ushort*)(smem + cur * 16384 + 8192);
    bf16x8 af[4], bfr[4];
#pragma unroll
    for (int i = 0; i < 4; i++)
      af[i] = *(const bf16x8*)&lAc[(wm * 64 + i * 16 + col) * 32 + quad * 8];
#pragma unroll
    for (int j = 0; j < 4; j++)
      bfr[j] = *(const bf16x8*)&lBc[(wn * 64 + j * 16 + col) * 32 + quad * 8];
#pragma unroll
    for (int i = 0; i < 4; i++)
#pragma unroll
      for (int j = 0; j < 4; j++)
        acc[i][j] = __builtin_amdgcn_mfma_f32_16x16x32_bf16(af[i], bfr[j], acc[i][j], 0, 0, 0);
  }
  __syncthreads();
  float* lCw = lC + wave * 16 * 68;
  int mW = mBase + wm * 64, nW = nBase + wn * 64;
  int b = z >> 2, q = z & 3;
#pragma unroll
  for (int i = 0; i < 4; i++) {
#pragma unroll
    for (int j = 0; j < 4; j++)
#pragma unroll
      for (int rg = 0; rg < 4; rg++)
        lCw[(quad * 4 + rg) * 68 + j * 16 + col] = acc[i][j][rg];
    int mrow0 = mW + i * 16;
    int rr = lane & 15, cc = lane >> 4;
    int n0 = nW + cc * 16;
    if (n0 < NN) {
      int ch = mrow0 + rr;
      float g = stg[ch];
      float rb = (bo[(size_t)z * 256 + ch] - stm[ch]) * g + beta[ch];
      float* C = out + (size_t)b * (CCH * QQ * NN)
               + (size_t)ch * (QQ * NN) + (size_t)q * NN + n0;
#pragma unroll
      for (int v = 0; v < 4; v++) {
        float4 f;
        f.x = lCw[rr * 68 + cc * 16 + v * 4 + 0] * g + rb;
        f.y = lCw[rr * 68 + cc * 16 + v * 4 + 1] * g + rb;
        f.z = lCw[rr * 68 + cc * 16 + v * 4 + 2] * g + rb;
        f.w = lCw[rr * 68 + cc * 16 + v * 4 + 3] * g + rb;
        *(float4*)(C + v * 4) = f;
      }
    }
  }
}

extern "C" void kernel_launch(void* const* d_in, const int* in_sizes, int n_in,
                              void* d_out, int out_size, void* d_ws, size_t ws_size,
                              hipStream_t stream) {
  const float* x     = (const float*)d_in[0];
  const float* Wq    = (const float*)d_in[1];
  const float* bq    = (const float*)d_in[2];
  const float* Wk    = (const float*)d_in[3];
  const float* bk    = (const float*)d_in[4];
  const float* Wv    = (const float*)d_in[5];
  const float* bv    = (const float*)d_in[6];
  const float* Wp    = (const float*)d_in[7];
  const float* bp    = (const float*)d_in[8];
  const float* gamma = (const float*)d_in[9];
  const float* beta  = (const float*)d_in[10];
  float* out = (float*)d_out;

  ushort* h    = (ushort*)d_ws;
  ushort* wq   = h;                      // 65536 each
  ushort* wk   = wq + 65536;
  ushort* wp   = wk + 65536;
  ushort* wvT  = wp + 65536;
  ushort* xb   = wvT + 65536;            // [32][256][1600]
  ushort* xT   = xb + (size_t)BQN * CCH * NN;   // [51200][256]
  ushort* Gh   = xT + (size_t)BQN * CCH * NN;   // [32][256][256]
  ushort* Gl   = Gh + (size_t)BQN * 65536;
  ushort* M1h  = Gl + (size_t)BQN * 65536;
  ushort* M1l  = M1h + (size_t)BQN * 65536;
  ushort* P    = M1l + (size_t)BQN * 65536;
  ushort* N1t  = P + (size_t)BQN * 65536;
  ushort* Tm   = N1t + (size_t)BQN * 65536;
  float*  S    = (float*)(Tm + (size_t)BQN * 65536);   // [32][256][256] fp32
  float*  Gp   = S + (size_t)BQN * 65536;              // [4][32][65536] fp32
  float*  r    = Gp + (size_t)4 * BQN * 65536;         // 8192
  float*  u    = r + 8192;
  float*  vv   = u + 8192;
  float*  pb   = vv + 8192;
  float*  bo   = pb + 8192;
  float*  diagacc = bo + 8192;           // 8192
  float*  tracc   = diagacc + 8192;      // 8192
  float*  gq   = tracc + 8192;           // 256
  float*  stm  = gq + 256;               // 256
  float*  stg  = stm + 256;              // 256

  quant_weights_kernel<<<1025, 256, 0, stream>>>(Wq, Wk, Wv, Wp, gamma,
                                                 wq, wk, wvT, wp, gq, r, diagacc, tracc);
  prep_kernel<<<dim3(NN / 64, CCH / 64, BQN), 256, 0, stream>>>(x, xb, xT, r);
  uv_kernel<<<dim3(BQN, 2), 256, 0, stream>>>(wq, wk, r, u, vv);
  // G = Xb Xb^T per bq, split-K=4 partials then reduce -> split bf16
  gram_part_kernel<<<dim3(2, 2, 4 * BQN), 256, 0, stream>>>(xb, Gp);
  gram_reduce_kernel<<<BQN, 256, 0, stream>>>(Gp, Gh, Gl);
  // M1 = wq * G (split B)
  gemm256<0><<<dim3(2, 2, BQN), 256, 0, stream>>>(
      wq, 0, nullptr, Gh, 65536, Gl, M1h, M1l, 65536);
  // S = M1 * wk^T (split A)
  gemm256<1><<<dim3(2, 2, BQN), 256, 0, stream>>>(
      M1h, 65536, M1l, wk, 0, nullptr, S, nullptr, 65536);
  softmax_kernel<<<BQN * CCH, 256, 0, stream>>>(S, u, vv, bq, bk, bv, P, pb);
  // N1t = (P * wvT^T)^T
  gemm256<2><<<dim3(2, 2, BQN), 256, 0, stream>>>(
      P, 65536, nullptr, wvT, 0, nullptr, N1t, nullptr, 65536);
  // T = wp * N1t^T
  gemm256<3><<<dim3(2, 2, BQN), 256, 0, stream>>>(
      wp, 0, nullptr, N1t, 65536, nullptr, Tm, nullptr, 65536);
  bo_kernel<<<BQN, 256, 0, stream>>>(wp, pb, bp, bo);
  // diag(T G T^T) and T.r partials for analytic BN stats
  tgt_kernel<<<dim3(2, 2, BQN), 256, 0, stream>>>(Tm, Gh, Gl, r, diagacc, tracc);
  chanstats_kernel<<<1, 256, 0, stream>>>(diagacc, tracc, bo, gq, stm, stg);
  // out = normalized(T * X^T + bo) written directly
  final_kernel<<<dim3(13, 2, BQN), 256, 0, stream>>>(Tm, xT, bo, stm, stg, beta, out);
}